// Round 16
// baseline (1276.757 us; speedup 1.0000x reference)
//
#include <hip/hip_runtime.h>
#include <math.h>

#define HID 25
#define STR 32   // padded node-feature row stride (128B rows)
#define CHUNK 1024
#define FBTHR 0.1f
#define RST 72   // LDS activation row stride in bf16 (144B; conflict-managed)
#define CEPT 32  // edges per thread in k_compact (8192/block)

typedef __attribute__((ext_vector_type(8))) short short8;
typedef __attribute__((ext_vector_type(4))) float f32x4;

__device__ __forceinline__ float gelu_f(float x) {
    return 0.5f * x * (1.0f + erff(x * 0.70710678118654752f));
}

// tanh-form gelu, 7 VALU ops. Max err ~1e-3 -> z-margin err << FBTHR;
// exact-erf fallback decides all near-margin gates.
__device__ __forceinline__ float gelu_fast(float x) {
    float x2 = x * x;
    float c = fmaf(0.1029461f, x2, 2.3022077f);
    float m = x * c;
    float E;
    asm("v_exp_f32 %0, %1" : "=v"(E) : "v"(m));
    float D = E + 1.0f;
    float R = __builtin_amdgcn_rcpf(D);
    return fmaf(-R, x, x);
}

__device__ __forceinline__ short f2bf(float f) {
    unsigned u = __float_as_uint(f);
    u = (u + 0x7fffu + ((u >> 16) & 1u)) >> 16;
    return (short)u;
}

// gather 4 consecutive MLP-input slots (k = grp*4 .. grp*4+3) for edge e
__device__ __forceinline__ void gather4(int e, int E, const int* __restrict__ ei,
                                        const float* __restrict__ xt6,
                                        const float* __restrict__ attr, int grp,
                                        float& v0, float& v1, float& v2, float& v3) {
    v0 = v1 = v2 = v3 = 0.f;
    if (e < E) {
        if (grp == 0) {
            const float4 f = *(const float4*)&xt6[(size_t)ei[e] * 8];
            v0 = f.x; v1 = f.y; v2 = f.z; v3 = f.w;
        } else if (grp == 1) {
            int s = ei[e], d = ei[E + e];
            const float2 lo = *(const float2*)&xt6[(size_t)s * 8 + 4];
            const float2 hi = *(const float2*)&xt6[(size_t)d * 8];
            v0 = lo.x; v1 = lo.y; v2 = hi.x; v3 = hi.y;
        } else if (grp == 2) {
            int d = ei[E + e];
            const float2 lo = *(const float2*)&xt6[(size_t)d * 8 + 2];
            const float2 hi = *(const float2*)&xt6[(size_t)d * 8 + 4];
            v0 = lo.x; v1 = lo.y; v2 = hi.x; v3 = hi.y;
        } else {
            v0 = attr[e];
        }
    }
}

// ---------------- node input linear + packed xt6 ----------------
__global__ void k_node_in(const float* __restrict__ x, const float* __restrict__ token,
                          const float* __restrict__ W, const float* __restrict__ b,
                          float* __restrict__ hn, float* __restrict__ xt6, int N) {
    int gid = blockIdx.x * blockDim.x + threadIdx.x;
    int n = gid >> 5, j = gid & 31;
    if (n >= N) return;
    if (j < 8) xt6[(size_t)n * 8 + j] = (j == 0) ? x[n] : ((j < 6) ? token[n * 5 + j - 1] : 0.f);
    if (j >= HID) return;
    float acc = b[j];
    acc += x[n] * W[j];
    #pragma unroll
    for (int i = 0; i < 5; i++) acc += token[n * 5 + i] * W[(i + 1) * HID + j];
    hn[(size_t)n * STR + j] = acc;
}

// ---------------- edge MLP via MFMA (bf16), col'-layout LDS, TWO tiles/iter ----------------
__global__ __launch_bounds__(256) void k_edge_mlp_mfma(
    const int* __restrict__ ei, const float* __restrict__ xt6,
    const float* __restrict__ attr, const float* __restrict__ gumbel,
    const float* __restrict__ W0, const float* __restrict__ b0,
    const float* __restrict__ W1, const float* __restrict__ b1,
    const float* __restrict__ W2, const float* __restrict__ b2,
    const float* __restrict__ W3, const float* __restrict__ b3,
    float* __restrict__ eval_, unsigned char* __restrict__ flagv,
    int E, int ntiles, int nwaves) {
    __shared__ short hbuf[4][2][16 * RST];
    const int lane = threadIdx.x & 63;
    const int wv = threadIdx.x >> 6;
    const int wid = blockIdx.x * 4 + wv;
    const int grp = lane >> 4, r2 = lane & 15;

    short8 w0f[4], w1f[2][4], w2f[2][4];
    #pragma unroll
    for (int nt = 0; nt < 4; nt++) {
        int col = r2 + 16 * nt;
        #pragma unroll
        for (int j = 0; j < 8; j++) {
            int k = grp * 4 + (j & 3) + 16 * (j >> 2);
            w0f[nt][j] = (k < 13 && col < 50) ? f2bf(W0[k * 50 + col]) : (short)0;
        }
    }
    #pragma unroll
    for (int kt = 0; kt < 2; kt++) {
        #pragma unroll
        for (int nt = 0; nt < 4; nt++) {
            int col = r2 + 16 * nt;
            #pragma unroll
            for (int j = 0; j < 8; j++) {
                int cW = (j & 3) * 16 + kt * 8 + grp * 2 + (j >> 2);
                w1f[kt][nt][j] = (cW < 50 && col < 50) ? f2bf(W1[cW * 50 + col]) : (short)0;
                w2f[kt][nt][j] = (cW < 50 && col < 50) ? f2bf(W2[cW * 50 + col]) : (short)0;
            }
        }
    }
    float b0v[4], b1v[4], b2v[4], w3dv[4];
    #pragma unroll
    for (int nt = 0; nt < 4; nt++) {
        int col = r2 + 16 * nt;
        b0v[nt] = (col < 50) ? b0[col] : 0.f;
        b1v[nt] = (col < 50) ? b1[col] : 0.f;
        b2v[nt] = (col < 50) ? b2[col] : 0.f;
        w3dv[nt] = (col < 50) ? (W3[col * 2 + 1] - W3[col * 2]) : 0.f;
    }
    const float b3d = b3[1] - b3[0];
    const f32x4 z4 = {0.f, 0.f, 0.f, 0.f};
    short* hbA = &hbuf[wv][0][0];
    short* hbB = &hbuf[wv][1][0];

    auto store4 = [&](short* hb, const f32x4& c0, const f32x4& c1,
                      const f32x4& c2, const f32x4& c3, const float* bv) {
        #pragma unroll
        for (int i = 0; i < 4; i++) {
            int row = grp * 4 + i;
            float v0 = gelu_fast(c0[i] + bv[0]);
            float v1 = gelu_fast(c1[i] + bv[1]);
            float v2 = gelu_fast(c2[i] + bv[2]);
            float v3 = gelu_fast(c3[i] + bv[3]);
            unsigned lo, hi;
            asm("v_cvt_pk_bf16_f32 %0, %1, %2" : "=v"(lo) : "v"(v0), "v"(v1));
            asm("v_cvt_pk_bf16_f32 %0, %1, %2" : "=v"(hi) : "v"(v2), "v"(v3));
            *(int2*)&hb[row * RST + r2 * 4] = make_int2((int)lo, (int)hi);
        }
    };
    auto load2 = [&](const short* hb, short8& k0, short8& k1) {
        k0 = *(const short8*)&hb[r2 * RST + 0 * 32 + grp * 8];
        k1 = *(const short8*)&hb[r2 * RST + 1 * 32 + grp * 8];
    };

    for (int t0 = wid * 2; t0 < ntiles; t0 += nwaves * 2) {
        const int baseA = t0 * 16, baseB = baseA + 16;

        float gA0, gA1, gA2, gA3, gB0, gB1, gB2, gB3;
        gather4(baseA + r2, E, ei, xt6, attr, grp, gA0, gA1, gA2, gA3);
        gather4(baseB + r2, E, ei, xt6, attr, grp, gB0, gB1, gB2, gB3);
        short8 aA = {f2bf(gA0), f2bf(gA1), f2bf(gA2), f2bf(gA3), 0, 0, 0, 0};
        short8 aB = {f2bf(gB0), f2bf(gB1), f2bf(gB2), f2bf(gB3), 0, 0, 0, 0};

        // ---- layer 0 (both tiles) ----
        f32x4 cA0 = __builtin_amdgcn_mfma_f32_16x16x32_bf16(aA, w0f[0], z4, 0, 0, 0);
        f32x4 cA1 = __builtin_amdgcn_mfma_f32_16x16x32_bf16(aA, w0f[1], z4, 0, 0, 0);
        f32x4 cA2 = __builtin_amdgcn_mfma_f32_16x16x32_bf16(aA, w0f[2], z4, 0, 0, 0);
        f32x4 cA3 = __builtin_amdgcn_mfma_f32_16x16x32_bf16(aA, w0f[3], z4, 0, 0, 0);
        f32x4 cB0 = __builtin_amdgcn_mfma_f32_16x16x32_bf16(aB, w0f[0], z4, 0, 0, 0);
        f32x4 cB1 = __builtin_amdgcn_mfma_f32_16x16x32_bf16(aB, w0f[1], z4, 0, 0, 0);
        f32x4 cB2 = __builtin_amdgcn_mfma_f32_16x16x32_bf16(aB, w0f[2], z4, 0, 0, 0);
        f32x4 cB3 = __builtin_amdgcn_mfma_f32_16x16x32_bf16(aB, w0f[3], z4, 0, 0, 0);
        store4(hbA, cA0, cA1, cA2, cA3, b0v);
        store4(hbB, cB0, cB1, cB2, cB3, b0v);

        // ---- layer 1 (both tiles) ----
        short8 kA0, kA1, kB0, kB1;
        load2(hbA, kA0, kA1);
        load2(hbB, kB0, kB1);
        cA0 = __builtin_amdgcn_mfma_f32_16x16x32_bf16(kA1, w1f[1][0],
              __builtin_amdgcn_mfma_f32_16x16x32_bf16(kA0, w1f[0][0], z4, 0, 0, 0), 0, 0, 0);
        cA1 = __builtin_amdgcn_mfma_f32_16x16x32_bf16(kA1, w1f[1][1],
              __builtin_amdgcn_mfma_f32_16x16x32_bf16(kA0, w1f[0][1], z4, 0, 0, 0), 0, 0, 0);
        cA2 = __builtin_amdgcn_mfma_f32_16x16x32_bf16(kA1, w1f[1][2],
              __builtin_amdgcn_mfma_f32_16x16x32_bf16(kA0, w1f[0][2], z4, 0, 0, 0), 0, 0, 0);
        cA3 = __builtin_amdgcn_mfma_f32_16x16x32_bf16(kA1, w1f[1][3],
              __builtin_amdgcn_mfma_f32_16x16x32_bf16(kA0, w1f[0][3], z4, 0, 0, 0), 0, 0, 0);
        cB0 = __builtin_amdgcn_mfma_f32_16x16x32_bf16(kB1, w1f[1][0],
              __builtin_amdgcn_mfma_f32_16x16x32_bf16(kB0, w1f[0][0], z4, 0, 0, 0), 0, 0, 0);
        cB1 = __builtin_amdgcn_mfma_f32_16x16x32_bf16(kB1, w1f[1][1],
              __builtin_amdgcn_mfma_f32_16x16x32_bf16(kB0, w1f[0][1], z4, 0, 0, 0), 0, 0, 0);
        cB2 = __builtin_amdgcn_mfma_f32_16x16x32_bf16(kB1, w1f[1][2],
              __builtin_amdgcn_mfma_f32_16x16x32_bf16(kB0, w1f[0][2], z4, 0, 0, 0), 0, 0, 0);
        cB3 = __builtin_amdgcn_mfma_f32_16x16x32_bf16(kB1, w1f[1][3],
              __builtin_amdgcn_mfma_f32_16x16x32_bf16(kB0, w1f[0][3], z4, 0, 0, 0), 0, 0, 0);
        store4(hbA, cA0, cA1, cA2, cA3, b1v);
        store4(hbB, cB0, cB1, cB2, cB3, b1v);

        // ---- layer 2 (both tiles) ----
        load2(hbA, kA0, kA1);
        load2(hbB, kB0, kB1);
        cA0 = __builtin_amdgcn_mfma_f32_16x16x32_bf16(kA1, w2f[1][0],
              __builtin_amdgcn_mfma_f32_16x16x32_bf16(kA0, w2f[0][0], z4, 0, 0, 0), 0, 0, 0);
        cA1 = __builtin_amdgcn_mfma_f32_16x16x32_bf16(kA1, w2f[1][1],
              __builtin_amdgcn_mfma_f32_16x16x32_bf16(kA0, w2f[0][1], z4, 0, 0, 0), 0, 0, 0);
        cA2 = __builtin_amdgcn_mfma_f32_16x16x32_bf16(kA1, w2f[1][2],
              __builtin_amdgcn_mfma_f32_16x16x32_bf16(kA0, w2f[0][2], z4, 0, 0, 0), 0, 0, 0);
        cA3 = __builtin_amdgcn_mfma_f32_16x16x32_bf16(kA1, w2f[1][3],
              __builtin_amdgcn_mfma_f32_16x16x32_bf16(kA0, w2f[0][3], z4, 0, 0, 0), 0, 0, 0);
        cB0 = __builtin_amdgcn_mfma_f32_16x16x32_bf16(kB1, w2f[1][0],
              __builtin_amdgcn_mfma_f32_16x16x32_bf16(kB0, w2f[0][0], z4, 0, 0, 0), 0, 0, 0);
        cB1 = __builtin_amdgcn_mfma_f32_16x16x32_bf16(kB1, w2f[1][1],
              __builtin_amdgcn_mfma_f32_16x16x32_bf16(kB0, w2f[0][1], z4, 0, 0, 0), 0, 0, 0);
        cB2 = __builtin_amdgcn_mfma_f32_16x16x32_bf16(kB1, w2f[1][2],
              __builtin_amdgcn_mfma_f32_16x16x32_bf16(kB0, w2f[0][2], z4, 0, 0, 0), 0, 0, 0);
        cB3 = __builtin_amdgcn_mfma_f32_16x16x32_bf16(kB1, w2f[1][3],
              __builtin_amdgcn_mfma_f32_16x16x32_bf16(kB0, w2f[0][3], z4, 0, 0, 0), 0, 0, 0);

        // ---- z-diff + reduce (both tiles) ----
        float zA0 = 0.f, zA1 = 0.f, zA2 = 0.f, zA3 = 0.f;
        float zB0 = 0.f, zB1 = 0.f, zB2 = 0.f, zB3 = 0.f;
        #pragma unroll
        for (int i = 0; i < 4; i++) {
            float hA0 = gelu_fast(cA0[i] + b2v[0]), hA1 = gelu_fast(cA1[i] + b2v[1]);
            float hA2 = gelu_fast(cA2[i] + b2v[2]), hA3 = gelu_fast(cA3[i] + b2v[3]);
            float hB0 = gelu_fast(cB0[i] + b2v[0]), hB1 = gelu_fast(cB1[i] + b2v[1]);
            float hB2 = gelu_fast(cB2[i] + b2v[2]), hB3 = gelu_fast(cB3[i] + b2v[3]);
            float zA = hA0 * w3dv[0] + hA1 * w3dv[1] + hA2 * w3dv[2] + hA3 * w3dv[3];
            float zB = hB0 * w3dv[0] + hB1 * w3dv[1] + hB2 * w3dv[2] + hB3 * w3dv[3];
            if (i == 0) { zA0 = zA; zB0 = zB; }
            else if (i == 1) { zA1 = zA; zB1 = zB; }
            else if (i == 2) { zA2 = zA; zB2 = zB; }
            else { zA3 = zA; zB3 = zB; }
        }
        #pragma unroll
        for (int off = 1; off < 16; off <<= 1) {
            zA0 += __shfl_xor(zA0, off); zA1 += __shfl_xor(zA1, off);
            zA2 += __shfl_xor(zA2, off); zA3 += __shfl_xor(zA3, off);
            zB0 += __shfl_xor(zB0, off); zB1 += __shfl_xor(zB1, off);
            zB2 += __shfl_xor(zB2, off); zB3 += __shfl_xor(zB3, off);
        }
        if (r2 < 4) {
            int eA = baseA + grp * 4 + r2;
            if (eA < E) {
                float zsel = (r2 == 0) ? zA0 : (r2 == 1) ? zA1 : (r2 == 2) ? zA2 : zA3;
                float g0v = gumbel[2 * (long long)eA], g1v = gumbel[2 * (long long)eA + 1];
                float m = zsel + b3d + g1v - g0v;
                eval_[eA] = (m > 0.f) ? 1.f : 0.f;
                flagv[eA] = (fabsf(m) < FBTHR) ? 1 : 0;
            }
            int eB = baseB + grp * 4 + r2;
            if (eB < E) {
                float zsel = (r2 == 0) ? zB0 : (r2 == 1) ? zB1 : (r2 == 2) ? zB2 : zB3;
                float g0v = gumbel[2 * (long long)eB], g1v = gumbel[2 * (long long)eB + 1];
                float m = zsel + b3d + g1v - g0v;
                eval_[eB] = (m > 0.f) ? 1.f : 0.f;
                flagv[eB] = (fabsf(m) < FBTHR) ? 1 : 0;
            }
        }
    }
}

// ---------------- block-aggregated flag -> list compaction ----------------
__global__ __launch_bounds__(256) void k_compact(const unsigned char* __restrict__ flagv,
                                                 int* __restrict__ flcnt,
                                                 int* __restrict__ fllist, int E) {
    __shared__ int s[256];
    __shared__ int sbase;
    const int t = threadIdx.x;
    const long long base = (long long)blockIdx.x * (256 * CEPT) + (long long)t * CEPT;

    unsigned char fl[CEPT];
    #pragma unroll
    for (int u = 0; u < CEPT; u += 16) {
        int4 w = make_int4(0, 0, 0, 0);
        if (base + u + 15 < (long long)E) {
            w = *(const int4*)&flagv[base + u];
        } else {
            #pragma unroll
            for (int b2 = 0; b2 < 16; b2++) {
                long long idx = base + u + b2;
                ((unsigned char*)&w)[b2] = (idx < (long long)E) ? flagv[idx] : 0;
            }
        }
        *(int4*)&fl[u] = w;
    }
    int cnt = 0;
    #pragma unroll
    for (int u = 0; u < CEPT; u++) cnt += fl[u];

    s[t] = cnt;
    __syncthreads();
    for (int off = 1; off < 256; off <<= 1) {
        int xv = (t >= off) ? s[t - off] : 0;
        __syncthreads();
        s[t] += xv;
        __syncthreads();
    }
    if (t == 255) sbase = (s[255] > 0) ? atomicAdd(flcnt, s[255]) : 0;
    __syncthreads();

    int pos = sbase + s[t] - cnt;
    #pragma unroll
    for (int u = 0; u < CEPT; u++) {
        if (fl[u]) fllist[pos++] = (int)(base + u);
    }
}

// ---------------- wave-cooperative exact-fp32 fallback ----------------
__global__ __launch_bounds__(256) void k_edge_fb(
    const int* __restrict__ ei, const float* __restrict__ xt6,
    const float* __restrict__ attr, const float* __restrict__ gumbel,
    const float* __restrict__ W0, const float* __restrict__ b0,
    const float* __restrict__ W1, const float* __restrict__ b1,
    const float* __restrict__ W2, const float* __restrict__ b2,
    const float* __restrict__ W3, const float* __restrict__ b3,
    const int* __restrict__ fllist, const int* __restrict__ flcnt,
    float* __restrict__ eval_, int E, int nwaves) {
    __shared__ float buf[4][2][2][64];
    const int lane = threadIdx.x & 63;
    const int wv = threadIdx.x >> 6;
    const int wid = blockIdx.x * 4 + wv;
    const int jw = (lane < 50) ? lane : 49;

    float w0r[16], w1r[52], w2r[52];
    #pragma unroll
    for (int k = 0; k < 13; k++) w0r[k] = W0[k * 50 + jw];
    w0r[13] = 0.f; w0r[14] = 0.f; w0r[15] = 0.f;
    #pragma unroll
    for (int k = 0; k < 50; k++) w1r[k] = W1[k * 50 + jw];
    w1r[50] = 0.f; w1r[51] = 0.f;
    #pragma unroll
    for (int k = 0; k < 50; k++) w2r[k] = W2[k * 50 + jw];
    w2r[50] = 0.f; w2r[51] = 0.f;
    const float b0r = b0[jw], b1r = b1[jw], b2r = b2[jw];
    const float b3_0 = b3[0], b3_1 = b3[1];
    const float w3d = (lane < 50) ? (W3[lane * 2 + 1] - W3[lane * 2]) : 0.f;

    const int g = lane >> 4, r = lane & 15;
    const int cnt = *flcnt;

    for (int base = wid * 2; base < cnt; base += nwaves * 2) {
        if (g < 2) {
            int idx = base + g;
            float val = 0.f;
            if (idx < cnt && r < 13) {
                int e = fllist[idx];
                if (r == 12) val = attr[e];
                else if (r < 6) val = xt6[(size_t)ei[e] * 8 + r];
                else val = xt6[(size_t)ei[E + e] * 8 + (r - 6)];
            }
            buf[wv][0][g][r] = val;
        }

        const float4* a4 = (const float4*)(&buf[wv][0][0][0]);
        const float4* c4 = (const float4*)(&buf[wv][0][1][0]);
        float tA = b0r, tB = b0r;
        #pragma unroll
        for (int c = 0; c < 4; c++) {
            float4 a = a4[c], b = c4[c];
            tA += a.x * w0r[4 * c];     tB += b.x * w0r[4 * c];
            tA += a.y * w0r[4 * c + 1]; tB += b.y * w0r[4 * c + 1];
            tA += a.z * w0r[4 * c + 2]; tB += b.z * w0r[4 * c + 2];
            tA += a.w * w0r[4 * c + 3]; tB += b.w * w0r[4 * c + 3];
        }
        buf[wv][1][0][lane] = gelu_f(tA);
        buf[wv][1][1][lane] = gelu_f(tB);

        const float4* p4 = (const float4*)(&buf[wv][1][0][0]);
        const float4* q4 = (const float4*)(&buf[wv][1][1][0]);
        tA = b1r; tB = b1r;
        #pragma unroll
        for (int c = 0; c < 13; c++) {
            float4 a = p4[c], b = q4[c];
            tA += a.x * w1r[4 * c];     tB += b.x * w1r[4 * c];
            tA += a.y * w1r[4 * c + 1]; tB += b.y * w1r[4 * c + 1];
            tA += a.z * w1r[4 * c + 2]; tB += b.z * w1r[4 * c + 2];
            tA += a.w * w1r[4 * c + 3]; tB += b.w * w1r[4 * c + 3];
        }
        buf[wv][0][0][lane] = gelu_f(tA);
        buf[wv][0][1][lane] = gelu_f(tB);

        tA = b2r; tB = b2r;
        #pragma unroll
        for (int c = 0; c < 13; c++) {
            float4 a = a4[c], b = c4[c];
            tA += a.x * w2r[4 * c];     tB += b.x * w2r[4 * c];
            tA += a.y * w2r[4 * c + 1]; tB += b.y * w2r[4 * c + 1];
            tA += a.z * w2r[4 * c + 2]; tB += b.z * w2r[4 * c + 2];
            tA += a.w * w2r[4 * c + 3]; tB += b.w * w2r[4 * c + 3];
        }
        float h3A = gelu_f(tA), h3B = gelu_f(tB);
        buf[wv][1][0][lane] = h3A;
        buf[wv][1][1][lane] = h3B;

        float zA = h3A * w3d, zB = h3B * w3d;
        #pragma unroll
        for (int off = 32; off > 0; off >>= 1) {
            zA += __shfl_xor(zA, off);
            zB += __shfl_xor(zB, off);
        }

        if (lane < 2) {
            int idx = base + lane;
            if (idx < cnt) {
                int e = fllist[idx];
                float z = (lane == 0) ? zA : zB;
                float g0v = gumbel[2 * (long long)e], g1v = gumbel[2 * (long long)e + 1];
                float m = z + (b3_1 - b3_0) + g1v - g0v;
                float dec;
                if (fabsf(m) < 1e-4f) {
                    float z0 = 0.f, z1 = 0.f;
                    for (int j = 0; j < 50; j++) {
                        float h = buf[wv][1][lane][j];
                        z0 += h * W3[2 * j];
                        z1 += h * W3[2 * j + 1];
                    }
                    z0 += b3_0; z1 += b3_1;
                    dec = (z1 + g1v > z0 + g0v) ? 1.f : 0.f;
                } else {
                    dec = (m > 0.f) ? 1.f : 0.f;
                }
                eval_[e] = dec;
            }
        }
    }
}

// ---------------- CSR build: histogram (x4) + scan + scatter(+pack 8B) ----------------
__global__ void k_hist(const int* __restrict__ ei, int* __restrict__ cnt, int E) {
    int i = blockIdx.x * blockDim.x + threadIdx.x;
    int e = i * 4;
    if (e + 3 < E) {
        int4 d = *(const int4*)&ei[E + e];
        atomicAdd(&cnt[d.x], 1); atomicAdd(&cnt[d.y], 1);
        atomicAdd(&cnt[d.z], 1); atomicAdd(&cnt[d.w], 1);
    } else {
        for (int u = e; u < E; u++) atomicAdd(&cnt[ei[E + u]], 1);
    }
}

__global__ void k_scan_partial(const int* __restrict__ cnt, int* __restrict__ bsum, int N) {
    __shared__ int s[256];
    int b = blockIdx.x, t = threadIdx.x;
    int base = b * CHUNK + t * 4;
    int sum = 0;
    #pragma unroll
    for (int u = 0; u < 4; u++) { int idx = base + u; if (idx < N) sum += cnt[idx]; }
    s[t] = sum; __syncthreads();
    for (int off = 128; off > 0; off >>= 1) {
        if (t < off) s[t] += s[t + off];
        __syncthreads();
    }
    if (t == 0) bsum[b] = s[0];
}

__global__ void k_scan_top(const int* __restrict__ bsum, int* __restrict__ boff,
                           int* __restrict__ rowptr, int nb, int N, int E) {
    if (threadIdx.x == 0 && blockIdx.x == 0) {
        int run = 0;
        for (int i = 0; i < nb; i++) { boff[i] = run; run += bsum[i]; }
        rowptr[N] = E;
    }
}

__global__ void k_scan_final(const int* __restrict__ cnt, const int* __restrict__ boff,
                             int* __restrict__ rowptr, int* __restrict__ wpos, int N) {
    __shared__ int s[256];
    int b = blockIdx.x, t = threadIdx.x;
    int base = b * CHUNK + t * 4;
    int v0 = 0, v1 = 0, v2 = 0, v3 = 0;
    if (base     < N) v0 = cnt[base];
    if (base + 1 < N) v1 = cnt[base + 1];
    if (base + 2 < N) v2 = cnt[base + 2];
    if (base + 3 < N) v3 = cnt[base + 3];
    int ts = v0 + v1 + v2 + v3;
    s[t] = ts; __syncthreads();
    for (int off = 1; off < 256; off <<= 1) {
        int xv = (t >= off) ? s[t - off] : 0;
        __syncthreads();
        s[t] += xv;
        __syncthreads();
    }
    int excl = s[t] - ts + boff[b];
    if (base     < N) { rowptr[base]     = excl;                 wpos[base]     = excl; }
    if (base + 1 < N) { int p = excl + v0;           rowptr[base + 1] = p; wpos[base + 1] = p; }
    if (base + 2 < N) { int p = excl + v0 + v1;      rowptr[base + 2] = p; wpos[base + 2] = p; }
    if (base + 3 < N) { int p = excl + v0 + v1 + v2; rowptr[base + 3] = p; wpos[base + 3] = p; }
}

// scatter + pack 8B per-edge record {src, bf16(attr)<<16 | bf16(gate)} at CSR position
__global__ void k_scatter(const int* __restrict__ ei, const float* __restrict__ attr,
                          const float* __restrict__ eval_, int* __restrict__ wpos,
                          int2* __restrict__ epack, int E) {
    int e = blockIdx.x * blockDim.x + threadIdx.x;
    if (e >= E) return;
    int d = ei[E + e];
    int p = atomicAdd(&wpos[d], 1);
    unsigned ab = ((unsigned)(unsigned short)f2bf(attr[e]) << 16)
                | (unsigned)(unsigned short)f2bf(eval_[e]);
    epack[p] = make_int2(ei[e], (int)ab);
}

// ---------------- per-layer node transform: q fp32, k/v packed bf16 (one 128B line) ----------------
__global__ void k_qkvs(const float* __restrict__ hn,
                       const float* __restrict__ Wq, const float* __restrict__ bq,
                       const float* __restrict__ Wk, const float* __restrict__ bk,
                       const float* __restrict__ Wv, const float* __restrict__ bv,
                       const float* __restrict__ Ws, const float* __restrict__ bs,
                       float* __restrict__ q, unsigned short* __restrict__ kvp,
                       float* __restrict__ hnext, int N) {
    __shared__ float sWq[625], sWk[625], sWv[625], sWs[625], sbq[25], sbk[25], sbv[25], sbs[25];
    for (int i = threadIdx.x; i < 625; i += blockDim.x) {
        sWq[i] = Wq[i]; sWk[i] = Wk[i]; sWv[i] = Wv[i]; sWs[i] = Ws[i];
    }
    if (threadIdx.x < 25) {
        sbq[threadIdx.x] = bq[threadIdx.x]; sbk[threadIdx.x] = bk[threadIdx.x];
        sbv[threadIdx.x] = bv[threadIdx.x]; sbs[threadIdx.x] = bs[threadIdx.x];
    }
    __syncthreads();
    int gid = blockIdx.x * blockDim.x + threadIdx.x;
    int n = gid >> 5, j = gid & 31;
    if (n >= N) return;
    if (j >= HID) {
        kvp[(size_t)n * 64 + j] = 0;
        kvp[(size_t)n * 64 + 32 + j] = 0;
        return;
    }
    float h[25];
    #pragma unroll
    for (int i = 0; i < 25; i++) h[i] = hn[(size_t)n * STR + i];
    float aq = sbq[j], ak = sbk[j], av = sbv[j], as = sbs[j];
    #pragma unroll
    for (int i = 0; i < 25; i++) {
        float hi = h[i];
        aq += hi * sWq[i * 25 + j];
        ak += hi * sWk[i * 25 + j];
        av += hi * sWv[i * 25 + j];
        as += hi * sWs[i * 25 + j];
    }
    q[(size_t)n * STR + j] = aq;
    hnext[(size_t)n * STR + j] = as;
    kvp[(size_t)n * 64 + j] = (unsigned short)f2bf(ak);
    kvp[(size_t)n * 64 + 32 + j] = (unsigned short)f2bf(av);
}

// ---------------- fused node-centric attention, 8 lanes/node, bf16 kv single-line ----------------
__global__ void k_attn_node(const int* __restrict__ rowptr, const int2* __restrict__ epack,
                            const float* __restrict__ q, const unsigned short* __restrict__ kvp,
                            const float* __restrict__ We, const float* __restrict__ be,
                            float* __restrict__ hnext, int N) {
    int gid = blockIdx.x * blockDim.x + threadIdx.x;
    int n = gid >> 3, sub = gid & 7;
    if (n >= N) return;
    const float scale = 0.44721359549995793f;

    float qr[25];
    #pragma unroll
    for (int i = 0; i < 25; i++) qr[i] = q[(size_t)n * STR + i];

    float qW0[5], qW1[5], qbe[5];
    #pragma unroll
    for (int h = 0; h < 5; h++) {
        float a0 = 0.f, a1 = 0.f, ab = 0.f;
        #pragma unroll
        for (int c = 0; c < 5; c++) {
            int i = h * 5 + c;
            a0 += qr[i] * We[i];
            a1 += qr[i] * We[25 + i];
            ab += qr[i] * be[i];
        }
        qW0[h] = a0; qW1[h] = a1; qbe[h] = ab;
    }

    float accV[25];
    #pragma unroll
    for (int i = 0; i < 25; i++) accV[i] = 0.f;
    float den[5] = {0, 0, 0, 0, 0}, sA[5] = {0, 0, 0, 0, 0}, sG[5] = {0, 0, 0, 0, 0};

    int beg = rowptr[n], end = rowptr[n + 1];
    for (int p = beg + sub; p < end; p += 8) {
        int2 ep = epack[p];
        int s = ep.x;
        unsigned ab = (unsigned)ep.y;
        float a_ = __uint_as_float(ab & 0xffff0000u);
        float gl = __uint_as_float(ab << 16);
        const unsigned* kw = (const unsigned*)(kvp + (size_t)s * 64);

        float al[5];
        #pragma unroll
        for (int h = 0; h < 5; h++) al[h] = qW0[h] * a_ + qW1[h] * gl + qbe[h];
        #pragma unroll
        for (int w = 0; w < 12; w++) {
            unsigned u = kw[w];
            al[(2 * w) / 5]     = fmaf(__uint_as_float(u << 16), qr[2 * w], al[(2 * w) / 5]);
            al[(2 * w + 1) / 5] = fmaf(__uint_as_float(u & 0xffff0000u), qr[2 * w + 1], al[(2 * w + 1) / 5]);
        }
        al[4] = fmaf(__uint_as_float(kw[12] << 16), qr[24], al[4]);

        float exh[5];
        #pragma unroll
        for (int h = 0; h < 5; h++) {
            float ex = __expf(al[h] * scale);
            exh[h] = ex;
            den[h] += ex;
            sA[h] += ex * a_;
            sG[h] += ex * gl;
        }
        #pragma unroll
        for (int w = 0; w < 12; w++) {
            unsigned u = kw[16 + w];
            accV[2 * w]     = fmaf(exh[(2 * w) / 5], __uint_as_float(u << 16), accV[2 * w]);
            accV[2 * w + 1] = fmaf(exh[(2 * w + 1) / 5], __uint_as_float(u & 0xffff0000u), accV[2 * w + 1]);
        }
        accV[24] = fmaf(exh[4], __uint_as_float(kw[28] << 16), accV[24]);
    }

    #pragma unroll
    for (int off = 1; off < 8; off <<= 1) {
        #pragma unroll
        for (int i = 0; i < 25; i++) accV[i] += __shfl_xor(accV[i], off);
        #pragma unroll
        for (int h = 0; h < 5; h++) {
            den[h] += __shfl_xor(den[h], off);
            sA[h] += __shfl_xor(sA[h], off);
            sG[h] += __shfl_xor(sG[h], off);
        }
    }

    if (sub == 0) {
        #pragma unroll
        for (int h = 0; h < 5; h++) {
            float inv = 1.f / (den[h] + 1e-16f);
            #pragma unroll
            for (int c = 0; c < 5; c++) {
                int i = h * 5 + c;
                float agg = (accV[i] + sA[h] * We[i] + sG[h] * We[25 + i] + den[h] * be[i]) * inv;
                hnext[(size_t)n * STR + i] += agg;
            }
        }
    }
}

// ---------------- output ----------------
__global__ void k_out(const float* __restrict__ hn, const float* __restrict__ W,
                      const float* __restrict__ b, float* __restrict__ out, int N) {
    int n = blockIdx.x * blockDim.x + threadIdx.x;
    if (n >= N) return;
    float acc = b[0];
    #pragma unroll
    for (int i = 0; i < 25; i++) acc += hn[(size_t)n * STR + i] * W[i];
    out[n] = 1.f / (1.f + expf(-acc));
}

extern "C" void kernel_launch(void* const* d_in, const int* in_sizes, int n_in,
                              void* d_out, int out_size, void* d_ws, size_t ws_size,
                              hipStream_t stream) {
    const float* x      = (const float*)d_in[0];
    const float* token  = (const float*)d_in[1];
    const float* attr   = (const float*)d_in[2];
    const float* gumbel = (const float*)d_in[3];
    const int*   ei     = (const int*)d_in[4];
    const float* W0 = (const float*)d_in[5];
    const float* b0 = (const float*)d_in[6];
    const float* W1 = (const float*)d_in[7];
    const float* b1 = (const float*)d_in[8];
    const float* W2 = (const float*)d_in[9];
    const float* b2 = (const float*)d_in[10];
    const float* W3 = (const float*)d_in[11];
    const float* b3 = (const float*)d_in[12];
    const float* ilW = (const float*)d_in[13];
    const float* ilb = (const float*)d_in[14];
    const float* Wq = (const float*)d_in[15];
    const float* bq = (const float*)d_in[16];
    const float* Wk = (const float*)d_in[17];
    const float* bk = (const float*)d_in[18];
    const float* Wv = (const float*)d_in[19];
    const float* bv = (const float*)d_in[20];
    const float* We = (const float*)d_in[21];
    const float* be = (const float*)d_in[22];
    const float* Ws = (const float*)d_in[23];
    const float* bs = (const float*)d_in[24];
    const float* oW = (const float*)d_in[25];
    const float* ob = (const float*)d_in[26];

    const int N = in_sizes[0];
    const int E = in_sizes[2];
    const int nb_chunk = (N + CHUNK - 1) / CHUNK;

    char* ws = (char*)d_ws;
    size_t off = 0;
    auto alloc = [&](size_t nb) -> void* {
        void* p = ws + off;
        off += (nb + 255) & ~(size_t)255;
        return p;
    };
    float* hnA    = (float*)alloc((size_t)N * STR * 4);
    float* hnB    = (float*)alloc((size_t)N * STR * 4);
    float* q      = (float*)alloc((size_t)N * STR * 4);
    unsigned short* kvp = (unsigned short*)alloc((size_t)N * 64 * 2);
    float* evalv  = (float*)alloc((size_t)E * 4);
    float* xt6    = (float*)alloc((size_t)N * 8 * 4);
    int*   cnt    = (int*)alloc((size_t)N * 4);
    int*   rowptr = (int*)alloc((size_t)(N + 1) * 4);
    int*   wpos   = (int*)alloc((size_t)N * 4);
    int*   bsum   = (int*)alloc((size_t)(nb_chunk + 1) * 4);
    int*   boff   = (int*)alloc((size_t)(nb_chunk + 1) * 4);
    int2*  epack  = (int2*)alloc((size_t)E * 8);
    int*   flcnt  = (int*)alloc(256);
    int*   fllist = (int*)alloc((size_t)E * 4);
    unsigned char* flagv = (unsigned char*)alloc((size_t)E);

    int nb_n32  = (N * STR + 255) / 256;
    int nb_n32b = (N * STR + 511) / 512;
    int nb_e    = (E + 255) / 256;
    int nb_e4   = ((E + 3) / 4 + 255) / 256;
    int nb_n8   = (N * 8 + 255) / 256;
    int nb_n    = (N + 255) / 256;
    int nb_cmp  = (E + 256 * CEPT - 1) / (256 * CEPT);

    const int mlp_blocks = 4096;
    const int mlp_waves  = mlp_blocks * 4;
    const int ntiles     = (E + 15) / 16;

    hipMemsetAsync(cnt, 0, (size_t)N * 4, stream);
    hipMemsetAsync(flcnt, 0, 4, stream);
    k_node_in<<<nb_n32, 256, 0, stream>>>(x, token, ilW, ilb, hnA, xt6, N);
    k_edge_mlp_mfma<<<mlp_blocks, 256, 0, stream>>>(ei, xt6, attr, gumbel,
                                                    W0, b0, W1, b1, W2, b2, W3, b3,
                                                    evalv, flagv, E, ntiles, mlp_waves);
    k_compact<<<nb_cmp, 256, 0, stream>>>(flagv, flcnt, fllist, E);
    k_edge_fb<<<2048, 256, 0, stream>>>(ei, xt6, attr, gumbel,
                                        W0, b0, W1, b1, W2, b2, W3, b3,
                                        fllist, flcnt, evalv, E, 2048 * 4);
    k_hist<<<nb_e4, 256, 0, stream>>>(ei, cnt, E);
    k_scan_partial<<<nb_chunk, 256, 0, stream>>>(cnt, bsum, N);
    k_scan_top<<<1, 64, 0, stream>>>(bsum, boff, rowptr, nb_chunk, N, E);
    k_scan_final<<<nb_chunk, 256, 0, stream>>>(cnt, boff, rowptr, wpos, N);
    k_scatter<<<nb_e, 256, 0, stream>>>(ei, attr, evalv, wpos, epack, E);

    float* cur = hnA;
    float* nxt = hnB;
    for (int l = 0; l < 3; l++) {
        k_qkvs<<<nb_n32b, 512, 0, stream>>>(cur, Wq + l * 625, bq + l * 25,
                                            Wk + l * 625, bk + l * 25,
                                            Wv + l * 625, bv + l * 25,
                                            Ws + l * 625, bs + l * 25,
                                            q, kvp, nxt, N);
        k_attn_node<<<nb_n8, 256, 0, stream>>>(rowptr, epack, q, kvp,
                                               We + l * 50, be + l * 25, nxt, N);
        float* t = cur; cur = nxt; nxt = t;
    }
    k_out<<<nb_n, 256, 0, stream>>>(cur, oW, ob, (float*)d_out, N);
}

// Round 17
// 1163.292 us; speedup vs baseline: 1.0975x; 1.0975x over previous
//
#include <hip/hip_runtime.h>
#include <math.h>

#define HID 25
#define STR 32   // padded node-feature row stride (128B rows)
#define CHUNK 1024
#define FBTHR 0.1f
#define RST 72   // LDS activation row stride in bf16 (144B; conflict-managed)
#define CEPT 32  // edges per thread in k_compact (8192/block)

typedef __attribute__((ext_vector_type(8))) short short8;
typedef __attribute__((ext_vector_type(4))) float f32x4;

__device__ __forceinline__ float gelu_f(float x) {
    return 0.5f * x * (1.0f + erff(x * 0.70710678118654752f));
}

// tanh-form gelu, 7 VALU ops. Max err ~1e-3 -> z-margin err << FBTHR;
// exact-erf fallback decides all near-margin gates.
__device__ __forceinline__ float gelu_fast(float x) {
    float x2 = x * x;
    float c = fmaf(0.1029461f, x2, 2.3022077f);
    float m = x * c;
    float E;
    asm("v_exp_f32 %0, %1" : "=v"(E) : "v"(m));
    float D = E + 1.0f;
    float R = __builtin_amdgcn_rcpf(D);
    return fmaf(-R, x, x);
}

__device__ __forceinline__ short f2bf(float f) {
    unsigned u = __float_as_uint(f);
    u = (u + 0x7fffu + ((u >> 16) & 1u)) >> 16;
    return (short)u;
}

// gather 4 consecutive MLP-input slots (k = grp*4 .. grp*4+3) for edge e
__device__ __forceinline__ void gather4(int e, int E, const int* __restrict__ ei,
                                        const float* __restrict__ xt6,
                                        const float* __restrict__ attr, int grp,
                                        float& v0, float& v1, float& v2, float& v3) {
    v0 = v1 = v2 = v3 = 0.f;
    if (e < E) {
        if (grp == 0) {
            const float4 f = *(const float4*)&xt6[(size_t)ei[e] * 8];
            v0 = f.x; v1 = f.y; v2 = f.z; v3 = f.w;
        } else if (grp == 1) {
            int s = ei[e], d = ei[E + e];
            const float2 lo = *(const float2*)&xt6[(size_t)s * 8 + 4];
            const float2 hi = *(const float2*)&xt6[(size_t)d * 8];
            v0 = lo.x; v1 = lo.y; v2 = hi.x; v3 = hi.y;
        } else if (grp == 2) {
            int d = ei[E + e];
            const float2 lo = *(const float2*)&xt6[(size_t)d * 8 + 2];
            const float2 hi = *(const float2*)&xt6[(size_t)d * 8 + 4];
            v0 = lo.x; v1 = lo.y; v2 = hi.x; v3 = hi.y;
        } else {
            v0 = attr[e];
        }
    }
}

// ---------------- node input linear + packed xt6 ----------------
__global__ void k_node_in(const float* __restrict__ x, const float* __restrict__ token,
                          const float* __restrict__ W, const float* __restrict__ b,
                          float* __restrict__ hn, float* __restrict__ xt6, int N) {
    int gid = blockIdx.x * blockDim.x + threadIdx.x;
    int n = gid >> 5, j = gid & 31;
    if (n >= N) return;
    if (j < 8) xt6[(size_t)n * 8 + j] = (j == 0) ? x[n] : ((j < 6) ? token[n * 5 + j - 1] : 0.f);
    if (j >= HID) return;
    float acc = b[j];
    acc += x[n] * W[j];
    #pragma unroll
    for (int i = 0; i < 5; i++) acc += token[n * 5 + i] * W[(i + 1) * HID + j];
    hn[(size_t)n * STR + j] = acc;
}

// ---------------- edge MLP via MFMA (bf16), col'-layout LDS ----------------
__global__ __launch_bounds__(256) void k_edge_mlp_mfma(
    const int* __restrict__ ei, const float* __restrict__ xt6,
    const float* __restrict__ attr, const float* __restrict__ gumbel,
    const float* __restrict__ W0, const float* __restrict__ b0,
    const float* __restrict__ W1, const float* __restrict__ b1,
    const float* __restrict__ W2, const float* __restrict__ b2,
    const float* __restrict__ W3, const float* __restrict__ b3,
    float* __restrict__ eval_, unsigned char* __restrict__ flagv,
    int E, int ntiles, int nwaves) {
    __shared__ short hbuf[4][16 * RST];
    const int lane = threadIdx.x & 63;
    const int wv = threadIdx.x >> 6;
    const int wid = blockIdx.x * 4 + wv;
    const int grp = lane >> 4, r2 = lane & 15;

    short8 w0f[4], w1f[2][4], w2f[2][4];
    #pragma unroll
    for (int nt = 0; nt < 4; nt++) {
        int col = r2 + 16 * nt;
        #pragma unroll
        for (int j = 0; j < 8; j++) {
            int k = grp * 4 + (j & 3) + 16 * (j >> 2);
            w0f[nt][j] = (k < 13 && col < 50) ? f2bf(W0[k * 50 + col]) : (short)0;
        }
    }
    #pragma unroll
    for (int kt = 0; kt < 2; kt++) {
        #pragma unroll
        for (int nt = 0; nt < 4; nt++) {
            int col = r2 + 16 * nt;
            #pragma unroll
            for (int j = 0; j < 8; j++) {
                int cW = (j & 3) * 16 + kt * 8 + grp * 2 + (j >> 2);
                w1f[kt][nt][j] = (cW < 50 && col < 50) ? f2bf(W1[cW * 50 + col]) : (short)0;
                w2f[kt][nt][j] = (cW < 50 && col < 50) ? f2bf(W2[cW * 50 + col]) : (short)0;
            }
        }
    }
    float b0v[4], b1v[4], b2v[4], w3dv[4];
    #pragma unroll
    for (int nt = 0; nt < 4; nt++) {
        int col = r2 + 16 * nt;
        b0v[nt] = (col < 50) ? b0[col] : 0.f;
        b1v[nt] = (col < 50) ? b1[col] : 0.f;
        b2v[nt] = (col < 50) ? b2[col] : 0.f;
        w3dv[nt] = (col < 50) ? (W3[col * 2 + 1] - W3[col * 2]) : 0.f;
    }
    const float b3d = b3[1] - b3[0];
    const f32x4 z4 = {0.f, 0.f, 0.f, 0.f};
    short* hb = &hbuf[wv][0];

    for (int t = wid; t < ntiles; t += nwaves) {
        const int base = t * 16;
        float g0, g1, g2, g3;
        gather4(base + r2, E, ei, xt6, attr, grp, g0, g1, g2, g3);
        short8 a0 = {f2bf(g0), f2bf(g1), f2bf(g2), f2bf(g3), 0, 0, 0, 0};

        // ---- layer 0 ----
        f32x4 c0 = __builtin_amdgcn_mfma_f32_16x16x32_bf16(a0, w0f[0], z4, 0, 0, 0);
        f32x4 c1 = __builtin_amdgcn_mfma_f32_16x16x32_bf16(a0, w0f[1], z4, 0, 0, 0);
        f32x4 c2 = __builtin_amdgcn_mfma_f32_16x16x32_bf16(a0, w0f[2], z4, 0, 0, 0);
        f32x4 c3 = __builtin_amdgcn_mfma_f32_16x16x32_bf16(a0, w0f[3], z4, 0, 0, 0);
        #pragma unroll
        for (int i = 0; i < 4; i++) {
            int row = grp * 4 + i;
            float v0 = gelu_fast(c0[i] + b0v[0]);
            float v1 = gelu_fast(c1[i] + b0v[1]);
            float v2 = gelu_fast(c2[i] + b0v[2]);
            float v3 = gelu_fast(c3[i] + b0v[3]);
            unsigned lo, hi;
            asm("v_cvt_pk_bf16_f32 %0, %1, %2" : "=v"(lo) : "v"(v0), "v"(v1));
            asm("v_cvt_pk_bf16_f32 %0, %1, %2" : "=v"(hi) : "v"(v2), "v"(v3));
            *(int2*)&hb[row * RST + r2 * 4] = make_int2((int)lo, (int)hi);
        }

        // ---- layer 1 ----
        {
            short8 k0 = *(const short8*)&hb[r2 * RST + 0 * 32 + grp * 8];
            short8 k1 = *(const short8*)&hb[r2 * RST + 1 * 32 + grp * 8];
            c0 = __builtin_amdgcn_mfma_f32_16x16x32_bf16(k1, w1f[1][0],
                 __builtin_amdgcn_mfma_f32_16x16x32_bf16(k0, w1f[0][0], z4, 0, 0, 0), 0, 0, 0);
            c1 = __builtin_amdgcn_mfma_f32_16x16x32_bf16(k1, w1f[1][1],
                 __builtin_amdgcn_mfma_f32_16x16x32_bf16(k0, w1f[0][1], z4, 0, 0, 0), 0, 0, 0);
            c2 = __builtin_amdgcn_mfma_f32_16x16x32_bf16(k1, w1f[1][2],
                 __builtin_amdgcn_mfma_f32_16x16x32_bf16(k0, w1f[0][2], z4, 0, 0, 0), 0, 0, 0);
            c3 = __builtin_amdgcn_mfma_f32_16x16x32_bf16(k1, w1f[1][3],
                 __builtin_amdgcn_mfma_f32_16x16x32_bf16(k0, w1f[0][3], z4, 0, 0, 0), 0, 0, 0);
        }
        #pragma unroll
        for (int i = 0; i < 4; i++) {
            int row = grp * 4 + i;
            float v0 = gelu_fast(c0[i] + b1v[0]);
            float v1 = gelu_fast(c1[i] + b1v[1]);
            float v2 = gelu_fast(c2[i] + b1v[2]);
            float v3 = gelu_fast(c3[i] + b1v[3]);
            unsigned lo, hi;
            asm("v_cvt_pk_bf16_f32 %0, %1, %2" : "=v"(lo) : "v"(v0), "v"(v1));
            asm("v_cvt_pk_bf16_f32 %0, %1, %2" : "=v"(hi) : "v"(v2), "v"(v3));
            *(int2*)&hb[row * RST + r2 * 4] = make_int2((int)lo, (int)hi);
        }

        // ---- layer 2 ----
        {
            short8 k0 = *(const short8*)&hb[r2 * RST + 0 * 32 + grp * 8];
            short8 k1 = *(const short8*)&hb[r2 * RST + 1 * 32 + grp * 8];
            c0 = __builtin_amdgcn_mfma_f32_16x16x32_bf16(k1, w2f[1][0],
                 __builtin_amdgcn_mfma_f32_16x16x32_bf16(k0, w2f[0][0], z4, 0, 0, 0), 0, 0, 0);
            c1 = __builtin_amdgcn_mfma_f32_16x16x32_bf16(k1, w2f[1][1],
                 __builtin_amdgcn_mfma_f32_16x16x32_bf16(k0, w2f[0][1], z4, 0, 0, 0), 0, 0, 0);
            c2 = __builtin_amdgcn_mfma_f32_16x16x32_bf16(k1, w2f[1][2],
                 __builtin_amdgcn_mfma_f32_16x16x32_bf16(k0, w2f[0][2], z4, 0, 0, 0), 0, 0, 0);
            c3 = __builtin_amdgcn_mfma_f32_16x16x32_bf16(k1, w2f[1][3],
                 __builtin_amdgcn_mfma_f32_16x16x32_bf16(k0, w2f[0][3], z4, 0, 0, 0), 0, 0, 0);
        }

        float z0 = 0.f, z1 = 0.f, z2 = 0.f, z3 = 0.f;
        #pragma unroll
        for (int i = 0; i < 4; i++) {
            float h0 = gelu_fast(c0[i] + b2v[0]), h1 = gelu_fast(c1[i] + b2v[1]);
            float h2 = gelu_fast(c2[i] + b2v[2]), h3 = gelu_fast(c3[i] + b2v[3]);
            float z = h0 * w3dv[0] + h1 * w3dv[1] + h2 * w3dv[2] + h3 * w3dv[3];
            if (i == 0) z0 = z; else if (i == 1) z1 = z; else if (i == 2) z2 = z; else z3 = z;
        }
        #pragma unroll
        for (int off = 1; off < 16; off <<= 1) {
            z0 += __shfl_xor(z0, off); z1 += __shfl_xor(z1, off);
            z2 += __shfl_xor(z2, off); z3 += __shfl_xor(z3, off);
        }
        if (r2 < 4) {
            int e2 = base + grp * 4 + r2;
            if (e2 < E) {
                float zsel = (r2 == 0) ? z0 : (r2 == 1) ? z1 : (r2 == 2) ? z2 : z3;
                float g0v = gumbel[2 * (long long)e2], g1v = gumbel[2 * (long long)e2 + 1];
                float m = zsel + b3d + g1v - g0v;
                eval_[e2] = (m > 0.f) ? 1.f : 0.f;
                flagv[e2] = (fabsf(m) < FBTHR) ? 1 : 0;
            }
        }
    }
}

// ---------------- block-aggregated flag -> list compaction ----------------
__global__ __launch_bounds__(256) void k_compact(const unsigned char* __restrict__ flagv,
                                                 int* __restrict__ flcnt,
                                                 int* __restrict__ fllist, int E) {
    __shared__ int s[256];
    __shared__ int sbase;
    const int t = threadIdx.x;
    const long long base = (long long)blockIdx.x * (256 * CEPT) + (long long)t * CEPT;

    unsigned char fl[CEPT];
    #pragma unroll
    for (int u = 0; u < CEPT; u += 16) {
        int4 w = make_int4(0, 0, 0, 0);
        if (base + u + 15 < (long long)E) {
            w = *(const int4*)&flagv[base + u];
        } else {
            #pragma unroll
            for (int b2 = 0; b2 < 16; b2++) {
                long long idx = base + u + b2;
                ((unsigned char*)&w)[b2] = (idx < (long long)E) ? flagv[idx] : 0;
            }
        }
        *(int4*)&fl[u] = w;
    }
    int cnt = 0;
    #pragma unroll
    for (int u = 0; u < CEPT; u++) cnt += fl[u];

    s[t] = cnt;
    __syncthreads();
    for (int off = 1; off < 256; off <<= 1) {
        int xv = (t >= off) ? s[t - off] : 0;
        __syncthreads();
        s[t] += xv;
        __syncthreads();
    }
    if (t == 255) sbase = (s[255] > 0) ? atomicAdd(flcnt, s[255]) : 0;
    __syncthreads();

    int pos = sbase + s[t] - cnt;
    #pragma unroll
    for (int u = 0; u < CEPT; u++) {
        if (fl[u]) fllist[pos++] = (int)(base + u);
    }
}

// ---------------- wave-cooperative exact-fp32 fallback ----------------
__global__ __launch_bounds__(256) void k_edge_fb(
    const int* __restrict__ ei, const float* __restrict__ xt6,
    const float* __restrict__ attr, const float* __restrict__ gumbel,
    const float* __restrict__ W0, const float* __restrict__ b0,
    const float* __restrict__ W1, const float* __restrict__ b1,
    const float* __restrict__ W2, const float* __restrict__ b2,
    const float* __restrict__ W3, const float* __restrict__ b3,
    const int* __restrict__ fllist, const int* __restrict__ flcnt,
    float* __restrict__ eval_, int E, int nwaves) {
    __shared__ float buf[4][2][2][64];
    const int lane = threadIdx.x & 63;
    const int wv = threadIdx.x >> 6;
    const int wid = blockIdx.x * 4 + wv;
    const int jw = (lane < 50) ? lane : 49;

    float w0r[16], w1r[52], w2r[52];
    #pragma unroll
    for (int k = 0; k < 13; k++) w0r[k] = W0[k * 50 + jw];
    w0r[13] = 0.f; w0r[14] = 0.f; w0r[15] = 0.f;
    #pragma unroll
    for (int k = 0; k < 50; k++) w1r[k] = W1[k * 50 + jw];
    w1r[50] = 0.f; w1r[51] = 0.f;
    #pragma unroll
    for (int k = 0; k < 50; k++) w2r[k] = W2[k * 50 + jw];
    w2r[50] = 0.f; w2r[51] = 0.f;
    const float b0r = b0[jw], b1r = b1[jw], b2r = b2[jw];
    const float b3_0 = b3[0], b3_1 = b3[1];
    const float w3d = (lane < 50) ? (W3[lane * 2 + 1] - W3[lane * 2]) : 0.f;

    const int g = lane >> 4, r = lane & 15;
    const int cnt = *flcnt;

    for (int base = wid * 2; base < cnt; base += nwaves * 2) {
        if (g < 2) {
            int idx = base + g;
            float val = 0.f;
            if (idx < cnt && r < 13) {
                int e = fllist[idx];
                if (r == 12) val = attr[e];
                else if (r < 6) val = xt6[(size_t)ei[e] * 8 + r];
                else val = xt6[(size_t)ei[E + e] * 8 + (r - 6)];
            }
            buf[wv][0][g][r] = val;
        }

        const float4* a4 = (const float4*)(&buf[wv][0][0][0]);
        const float4* c4 = (const float4*)(&buf[wv][0][1][0]);
        float tA = b0r, tB = b0r;
        #pragma unroll
        for (int c = 0; c < 4; c++) {
            float4 a = a4[c], b = c4[c];
            tA += a.x * w0r[4 * c];     tB += b.x * w0r[4 * c];
            tA += a.y * w0r[4 * c + 1]; tB += b.y * w0r[4 * c + 1];
            tA += a.z * w0r[4 * c + 2]; tB += b.z * w0r[4 * c + 2];
            tA += a.w * w0r[4 * c + 3]; tB += b.w * w0r[4 * c + 3];
        }
        buf[wv][1][0][lane] = gelu_f(tA);
        buf[wv][1][1][lane] = gelu_f(tB);

        const float4* p4 = (const float4*)(&buf[wv][1][0][0]);
        const float4* q4 = (const float4*)(&buf[wv][1][1][0]);
        tA = b1r; tB = b1r;
        #pragma unroll
        for (int c = 0; c < 13; c++) {
            float4 a = p4[c], b = q4[c];
            tA += a.x * w1r[4 * c];     tB += b.x * w1r[4 * c];
            tA += a.y * w1r[4 * c + 1]; tB += b.y * w1r[4 * c + 1];
            tA += a.z * w1r[4 * c + 2]; tB += b.z * w1r[4 * c + 2];
            tA += a.w * w1r[4 * c + 3]; tB += b.w * w1r[4 * c + 3];
        }
        buf[wv][0][0][lane] = gelu_f(tA);
        buf[wv][0][1][lane] = gelu_f(tB);

        tA = b2r; tB = b2r;
        #pragma unroll
        for (int c = 0; c < 13; c++) {
            float4 a = a4[c], b = c4[c];
            tA += a.x * w2r[4 * c];     tB += b.x * w2r[4 * c];
            tA += a.y * w2r[4 * c + 1]; tB += b.y * w2r[4 * c + 1];
            tA += a.z * w2r[4 * c + 2]; tB += b.z * w2r[4 * c + 2];
            tA += a.w * w2r[4 * c + 3]; tB += b.w * w2r[4 * c + 3];
        }
        float h3A = gelu_f(tA), h3B = gelu_f(tB);
        buf[wv][1][0][lane] = h3A;
        buf[wv][1][1][lane] = h3B;

        float zA = h3A * w3d, zB = h3B * w3d;
        #pragma unroll
        for (int off = 32; off > 0; off >>= 1) {
            zA += __shfl_xor(zA, off);
            zB += __shfl_xor(zB, off);
        }

        if (lane < 2) {
            int idx = base + lane;
            if (idx < cnt) {
                int e = fllist[idx];
                float z = (lane == 0) ? zA : zB;
                float g0v = gumbel[2 * (long long)e], g1v = gumbel[2 * (long long)e + 1];
                float m = z + (b3_1 - b3_0) + g1v - g0v;
                float dec;
                if (fabsf(m) < 1e-4f) {
                    float z0 = 0.f, z1 = 0.f;
                    for (int j = 0; j < 50; j++) {
                        float h = buf[wv][1][lane][j];
                        z0 += h * W3[2 * j];
                        z1 += h * W3[2 * j + 1];
                    }
                    z0 += b3_0; z1 += b3_1;
                    dec = (z1 + g1v > z0 + g0v) ? 1.f : 0.f;
                } else {
                    dec = (m > 0.f) ? 1.f : 0.f;
                }
                eval_[e] = dec;
            }
        }
    }
}

// ---------------- CSR build: histogram (x4) + scan + scatter(+pack 8B) ----------------
__global__ void k_hist(const int* __restrict__ ei, int* __restrict__ cnt, int E) {
    int i = blockIdx.x * blockDim.x + threadIdx.x;
    int e = i * 4;
    if (e + 3 < E) {
        int4 d = *(const int4*)&ei[E + e];
        atomicAdd(&cnt[d.x], 1); atomicAdd(&cnt[d.y], 1);
        atomicAdd(&cnt[d.z], 1); atomicAdd(&cnt[d.w], 1);
    } else {
        for (int u = e; u < E; u++) atomicAdd(&cnt[ei[E + u]], 1);
    }
}

__global__ void k_scan_partial(const int* __restrict__ cnt, int* __restrict__ bsum, int N) {
    __shared__ int s[256];
    int b = blockIdx.x, t = threadIdx.x;
    int base = b * CHUNK + t * 4;
    int sum = 0;
    #pragma unroll
    for (int u = 0; u < 4; u++) { int idx = base + u; if (idx < N) sum += cnt[idx]; }
    s[t] = sum; __syncthreads();
    for (int off = 128; off > 0; off >>= 1) {
        if (t < off) s[t] += s[t + off];
        __syncthreads();
    }
    if (t == 0) bsum[b] = s[0];
}

__global__ void k_scan_top(const int* __restrict__ bsum, int* __restrict__ boff,
                           int* __restrict__ rowptr, int nb, int N, int E) {
    if (threadIdx.x == 0 && blockIdx.x == 0) {
        int run = 0;
        for (int i = 0; i < nb; i++) { boff[i] = run; run += bsum[i]; }
        rowptr[N] = E;
    }
}

__global__ void k_scan_final(const int* __restrict__ cnt, const int* __restrict__ boff,
                             int* __restrict__ rowptr, int* __restrict__ wpos, int N) {
    __shared__ int s[256];
    int b = blockIdx.x, t = threadIdx.x;
    int base = b * CHUNK + t * 4;
    int v0 = 0, v1 = 0, v2 = 0, v3 = 0;
    if (base     < N) v0 = cnt[base];
    if (base + 1 < N) v1 = cnt[base + 1];
    if (base + 2 < N) v2 = cnt[base + 2];
    if (base + 3 < N) v3 = cnt[base + 3];
    int ts = v0 + v1 + v2 + v3;
    s[t] = ts; __syncthreads();
    for (int off = 1; off < 256; off <<= 1) {
        int xv = (t >= off) ? s[t - off] : 0;
        __syncthreads();
        s[t] += xv;
        __syncthreads();
    }
    int excl = s[t] - ts + boff[b];
    if (base     < N) { rowptr[base]     = excl;                 wpos[base]     = excl; }
    if (base + 1 < N) { int p = excl + v0;           rowptr[base + 1] = p; wpos[base + 1] = p; }
    if (base + 2 < N) { int p = excl + v0 + v1;      rowptr[base + 2] = p; wpos[base + 2] = p; }
    if (base + 3 < N) { int p = excl + v0 + v1 + v2; rowptr[base + 3] = p; wpos[base + 3] = p; }
}

// scatter + pack 8B per-edge record {src, bf16(attr)<<16 | bf16(gate)} at CSR position
__global__ void k_scatter(const int* __restrict__ ei, const float* __restrict__ attr,
                          const float* __restrict__ eval_, int* __restrict__ wpos,
                          int2* __restrict__ epack, int E) {
    int e = blockIdx.x * blockDim.x + threadIdx.x;
    if (e >= E) return;
    int d = ei[E + e];
    int p = atomicAdd(&wpos[d], 1);
    unsigned ab = ((unsigned)(unsigned short)f2bf(attr[e]) << 16)
                | (unsigned)(unsigned short)f2bf(eval_[e]);
    epack[p] = make_int2(ei[e], (int)ab);
}

// ---------------- per-layer node transform: q fp32, k/v packed bf16 (one 128B line) ----------------
__global__ void k_qkvs(const float* __restrict__ hn,
                       const float* __restrict__ Wq, const float* __restrict__ bq,
                       const float* __restrict__ Wk, const float* __restrict__ bk,
                       const float* __restrict__ Wv, const float* __restrict__ bv,
                       const float* __restrict__ Ws, const float* __restrict__ bs,
                       float* __restrict__ q, unsigned short* __restrict__ kvp,
                       float* __restrict__ hnext, int N) {
    __shared__ float sWq[625], sWk[625], sWv[625], sWs[625], sbq[25], sbk[25], sbv[25], sbs[25];
    for (int i = threadIdx.x; i < 625; i += blockDim.x) {
        sWq[i] = Wq[i]; sWk[i] = Wk[i]; sWv[i] = Wv[i]; sWs[i] = Ws[i];
    }
    if (threadIdx.x < 25) {
        sbq[threadIdx.x] = bq[threadIdx.x]; sbk[threadIdx.x] = bk[threadIdx.x];
        sbv[threadIdx.x] = bv[threadIdx.x]; sbs[threadIdx.x] = bs[threadIdx.x];
    }
    __syncthreads();
    int gid = blockIdx.x * blockDim.x + threadIdx.x;
    int n = gid >> 5, j = gid & 31;
    if (n >= N) return;
    if (j >= HID) {
        kvp[(size_t)n * 64 + j] = 0;
        kvp[(size_t)n * 64 + 32 + j] = 0;
        return;
    }
    float h[25];
    #pragma unroll
    for (int i = 0; i < 25; i++) h[i] = hn[(size_t)n * STR + i];
    float aq = sbq[j], ak = sbk[j], av = sbv[j], as = sbs[j];
    #pragma unroll
    for (int i = 0; i < 25; i++) {
        float hi = h[i];
        aq += hi * sWq[i * 25 + j];
        ak += hi * sWk[i * 25 + j];
        av += hi * sWv[i * 25 + j];
        as += hi * sWs[i * 25 + j];
    }
    q[(size_t)n * STR + j] = aq;
    hnext[(size_t)n * STR + j] = as;
    kvp[(size_t)n * 64 + j] = (unsigned short)f2bf(ak);
    kvp[(size_t)n * 64 + 32 + j] = (unsigned short)f2bf(av);
}

// ---------------- fused node-centric attention, 8 lanes/node, bf16 kv single-line ----------------
__global__ void k_attn_node(const int* __restrict__ rowptr, const int2* __restrict__ epack,
                            const float* __restrict__ q, const unsigned short* __restrict__ kvp,
                            const float* __restrict__ We, const float* __restrict__ be,
                            float* __restrict__ hnext, int N) {
    int gid = blockIdx.x * blockDim.x + threadIdx.x;
    int n = gid >> 3, sub = gid & 7;
    if (n >= N) return;
    const float scale = 0.44721359549995793f;

    float qr[25];
    #pragma unroll
    for (int i = 0; i < 25; i++) qr[i] = q[(size_t)n * STR + i];

    float qW0[5], qW1[5], qbe[5];
    #pragma unroll
    for (int h = 0; h < 5; h++) {
        float a0 = 0.f, a1 = 0.f, ab = 0.f;
        #pragma unroll
        for (int c = 0; c < 5; c++) {
            int i = h * 5 + c;
            a0 += qr[i] * We[i];
            a1 += qr[i] * We[25 + i];
            ab += qr[i] * be[i];
        }
        qW0[h] = a0; qW1[h] = a1; qbe[h] = ab;
    }

    float accV[25];
    #pragma unroll
    for (int i = 0; i < 25; i++) accV[i] = 0.f;
    float den[5] = {0, 0, 0, 0, 0}, sA[5] = {0, 0, 0, 0, 0}, sG[5] = {0, 0, 0, 0, 0};

    int beg = rowptr[n], end = rowptr[n + 1];
    for (int p = beg + sub; p < end; p += 8) {
        int2 ep = epack[p];
        int s = ep.x;
        unsigned ab = (unsigned)ep.y;
        float a_ = __uint_as_float(ab & 0xffff0000u);
        float gl = __uint_as_float(ab << 16);
        const unsigned* kw = (const unsigned*)(kvp + (size_t)s * 64);

        float al[5];
        #pragma unroll
        for (int h = 0; h < 5; h++) al[h] = qW0[h] * a_ + qW1[h] * gl + qbe[h];
        #pragma unroll
        for (int w = 0; w < 12; w++) {
            unsigned u = kw[w];
            al[(2 * w) / 5]     = fmaf(__uint_as_float(u << 16), qr[2 * w], al[(2 * w) / 5]);
            al[(2 * w + 1) / 5] = fmaf(__uint_as_float(u & 0xffff0000u), qr[2 * w + 1], al[(2 * w + 1) / 5]);
        }
        al[4] = fmaf(__uint_as_float(kw[12] << 16), qr[24], al[4]);

        float exh[5];
        #pragma unroll
        for (int h = 0; h < 5; h++) {
            float ex = __expf(al[h] * scale);
            exh[h] = ex;
            den[h] += ex;
            sA[h] += ex * a_;
            sG[h] += ex * gl;
        }
        #pragma unroll
        for (int w = 0; w < 12; w++) {
            unsigned u = kw[16 + w];
            accV[2 * w]     = fmaf(exh[(2 * w) / 5], __uint_as_float(u << 16), accV[2 * w]);
            accV[2 * w + 1] = fmaf(exh[(2 * w + 1) / 5], __uint_as_float(u & 0xffff0000u), accV[2 * w + 1]);
        }
        accV[24] = fmaf(exh[4], __uint_as_float(kw[28] << 16), accV[24]);
    }

    #pragma unroll
    for (int off = 1; off < 8; off <<= 1) {
        #pragma unroll
        for (int i = 0; i < 25; i++) accV[i] += __shfl_xor(accV[i], off);
        #pragma unroll
        for (int h = 0; h < 5; h++) {
            den[h] += __shfl_xor(den[h], off);
            sA[h] += __shfl_xor(sA[h], off);
            sG[h] += __shfl_xor(sG[h], off);
        }
    }

    if (sub == 0) {
        #pragma unroll
        for (int h = 0; h < 5; h++) {
            float inv = 1.f / (den[h] + 1e-16f);
            #pragma unroll
            for (int c = 0; c < 5; c++) {
                int i = h * 5 + c;
                float agg = (accV[i] + sA[h] * We[i] + sG[h] * We[25 + i] + den[h] * be[i]) * inv;
                hnext[(size_t)n * STR + i] += agg;
            }
        }
    }
}

// ---------------- output ----------------
__global__ void k_out(const float* __restrict__ hn, const float* __restrict__ W,
                      const float* __restrict__ b, float* __restrict__ out, int N) {
    int n = blockIdx.x * blockDim.x + threadIdx.x;
    if (n >= N) return;
    float acc = b[0];
    #pragma unroll
    for (int i = 0; i < 25; i++) acc += hn[(size_t)n * STR + i] * W[i];
    out[n] = 1.f / (1.f + expf(-acc));
}

extern "C" void kernel_launch(void* const* d_in, const int* in_sizes, int n_in,
                              void* d_out, int out_size, void* d_ws, size_t ws_size,
                              hipStream_t stream) {
    const float* x      = (const float*)d_in[0];
    const float* token  = (const float*)d_in[1];
    const float* attr   = (const float*)d_in[2];
    const float* gumbel = (const float*)d_in[3];
    const int*   ei     = (const int*)d_in[4];
    const float* W0 = (const float*)d_in[5];
    const float* b0 = (const float*)d_in[6];
    const float* W1 = (const float*)d_in[7];
    const float* b1 = (const float*)d_in[8];
    const float* W2 = (const float*)d_in[9];
    const float* b2 = (const float*)d_in[10];
    const float* W3 = (const float*)d_in[11];
    const float* b3 = (const float*)d_in[12];
    const float* ilW = (const float*)d_in[13];
    const float* ilb = (const float*)d_in[14];
    const float* Wq = (const float*)d_in[15];
    const float* bq = (const float*)d_in[16];
    const float* Wk = (const float*)d_in[17];
    const float* bk = (const float*)d_in[18];
    const float* Wv = (const float*)d_in[19];
    const float* bv = (const float*)d_in[20];
    const float* We = (const float*)d_in[21];
    const float* be = (const float*)d_in[22];
    const float* Ws = (const float*)d_in[23];
    const float* bs = (const float*)d_in[24];
    const float* oW = (const float*)d_in[25];
    const float* ob = (const float*)d_in[26];

    const int N = in_sizes[0];
    const int E = in_sizes[2];
    const int nb_chunk = (N + CHUNK - 1) / CHUNK;

    char* ws = (char*)d_ws;
    size_t off = 0;
    auto alloc = [&](size_t nb) -> void* {
        void* p = ws + off;
        off += (nb + 255) & ~(size_t)255;
        return p;
    };
    float* hnA    = (float*)alloc((size_t)N * STR * 4);
    float* hnB    = (float*)alloc((size_t)N * STR * 4);
    float* q      = (float*)alloc((size_t)N * STR * 4);
    unsigned short* kvp = (unsigned short*)alloc((size_t)N * 64 * 2);
    float* evalv  = (float*)alloc((size_t)E * 4);
    float* xt6    = (float*)alloc((size_t)N * 8 * 4);
    int*   cnt    = (int*)alloc((size_t)N * 4);
    int*   rowptr = (int*)alloc((size_t)(N + 1) * 4);
    int*   wpos   = (int*)alloc((size_t)N * 4);
    int*   bsum   = (int*)alloc((size_t)(nb_chunk + 1) * 4);
    int*   boff   = (int*)alloc((size_t)(nb_chunk + 1) * 4);
    int2*  epack  = (int2*)alloc((size_t)E * 8);
    int*   flcnt  = (int*)alloc(256);
    int*   fllist = (int*)alloc((size_t)E * 4);
    unsigned char* flagv = (unsigned char*)alloc((size_t)E);

    int nb_n32  = (N * STR + 255) / 256;
    int nb_n32b = (N * STR + 511) / 512;
    int nb_e    = (E + 255) / 256;
    int nb_e4   = ((E + 3) / 4 + 255) / 256;
    int nb_n8   = (N * 8 + 255) / 256;
    int nb_n    = (N + 255) / 256;
    int nb_cmp  = (E + 256 * CEPT - 1) / (256 * CEPT);

    const int mlp_blocks = 4096;
    const int mlp_waves  = mlp_blocks * 4;
    const int ntiles     = (E + 15) / 16;

    hipMemsetAsync(cnt, 0, (size_t)N * 4, stream);
    hipMemsetAsync(flcnt, 0, 4, stream);
    k_node_in<<<nb_n32, 256, 0, stream>>>(x, token, ilW, ilb, hnA, xt6, N);
    k_edge_mlp_mfma<<<mlp_blocks, 256, 0, stream>>>(ei, xt6, attr, gumbel,
                                                    W0, b0, W1, b1, W2, b2, W3, b3,
                                                    evalv, flagv, E, ntiles, mlp_waves);
    k_compact<<<nb_cmp, 256, 0, stream>>>(flagv, flcnt, fllist, E);
    k_edge_fb<<<2048, 256, 0, stream>>>(ei, xt6, attr, gumbel,
                                        W0, b0, W1, b1, W2, b2, W3, b3,
                                        fllist, flcnt, evalv, E, 2048 * 4);
    k_hist<<<nb_e4, 256, 0, stream>>>(ei, cnt, E);
    k_scan_partial<<<nb_chunk, 256, 0, stream>>>(cnt, bsum, N);
    k_scan_top<<<1, 64, 0, stream>>>(bsum, boff, rowptr, nb_chunk, N, E);
    k_scan_final<<<nb_chunk, 256, 0, stream>>>(cnt, boff, rowptr, wpos, N);
    k_scatter<<<nb_e, 256, 0, stream>>>(ei, attr, evalv, wpos, epack, E);

    float* cur = hnA;
    float* nxt = hnB;
    for (int l = 0; l < 3; l++) {
        k_qkvs<<<nb_n32b, 512, 0, stream>>>(cur, Wq + l * 625, bq + l * 25,
                                            Wk + l * 625, bk + l * 25,
                                            Wv + l * 625, bv + l * 25,
                                            Ws + l * 625, bs + l * 25,
                                            q, kvp, nxt, N);
        k_attn_node<<<nb_n8, 256, 0, stream>>>(rowptr, epack, q, kvp,
                                               We + l * 50, be + l * 25, nxt, N);
        float* t = cur; cur = nxt; nxt = t;
    }
    k_out<<<nb_n, 256, 0, stream>>>(cur, oW, ob, (float*)d_out, N);
}